// Round 1
// baseline (21867.253 us; speedup 1.0000x reference)
//
#include <hip/hip_runtime.h>

#define NN 100000
#define DD 128
#define NE 3200000

// ---------------- GEMM: g[m,n] = sum_k h[m,k] * W[n,k] + b[n] ----------------
// Block: 256 threads; tile = 64 rows x 128 cols; per-thread 4 rows x 8 cols.
// W (128x128 f32, 64 KB) staged in LDS with a 16B-chunk XOR swizzle so the
// per-lane feature reads (n = tc + 16*i) spread across bank quad-groups
// (2-way max, which is free on CDNA4).
__global__ __launch_bounds__(256) void gemm_xwt(const float* __restrict__ h,
                                                const float* __restrict__ W,
                                                const float* __restrict__ b,
                                                float* __restrict__ g) {
    __shared__ float Wl[128 * 128];
    const int t = threadIdx.x;
    // stage W: 16 float4 per thread; chunk c = k>>2 stored at c ^ (n&7)
    for (int i = t * 4; i < 128 * 128; i += 256 * 4) {
        const int n = i >> 7;
        const int k = i & 127;
        const float4 w = *(const float4*)&W[i];
        *(float4*)&Wl[(n << 7) + ((((k >> 2) ^ (n & 7)) << 2))] = w;
    }
    __syncthreads();

    const int tc = t & 15;        // feature group: n = tc + 16*i
    const int tr = t >> 4;        // row group: 4 rows each
    const int r0 = blockIdx.x * 64 + tr * 4;

    int rr[4];
#pragma unroll
    for (int j = 0; j < 4; ++j) rr[j] = min(r0 + j, NN - 1);

    float acc[4][8];
#pragma unroll
    for (int i = 0; i < 8; ++i) {
        const float bv = b[tc + 16 * i];
#pragma unroll
        for (int j = 0; j < 4; ++j) acc[j][i] = bv;
    }

#pragma unroll 2
    for (int k0 = 0; k0 < 128; k0 += 4) {
        float4 hv[4];
#pragma unroll
        for (int j = 0; j < 4; ++j)
            hv[j] = *(const float4*)&h[(size_t)rr[j] * DD + k0];
#pragma unroll
        for (int i = 0; i < 8; ++i) {
            const int n = tc + 16 * i;
            const float4 wv =
                *(const float4*)&Wl[(n << 7) + ((((k0 >> 2) ^ (n & 7)) << 2))];
#pragma unroll
            for (int j = 0; j < 4; ++j) {
                acc[j][i] += hv[j].x * wv.x;
                acc[j][i] += hv[j].y * wv.y;
                acc[j][i] += hv[j].z * wv.z;
                acc[j][i] += hv[j].w * wv.w;
            }
        }
    }

#pragma unroll
    for (int j = 0; j < 4; ++j) {
        const int r = r0 + j;
        if (r < NN) {
#pragma unroll
            for (int i = 0; i < 8; ++i)
                g[(size_t)r * DD + tc + 16 * i] = acc[j][i];
        }
    }
}

// ---------------- SpMM: y[rows[e]] += vals[e] * g[cols[e]] (atomic) ----------
// 32 threads per edge, float4 over the 128 features.
__global__ __launch_bounds__(256) void spmm_at(const float* __restrict__ vals,
                                               const int* __restrict__ rows,
                                               const int* __restrict__ cols,
                                               const float* __restrict__ g,
                                               float* __restrict__ y) {
    const int gid = blockIdx.x * 256 + threadIdx.x;
    const int f4 = (gid & 31) << 2;
    const int estride = (gridDim.x * 256) >> 5;
    for (int e = gid >> 5; e < NE; e += estride) {
        const float v = vals[e];
        const int r = rows[e];
        const int c = cols[e];
        const float4 gv = *(const float4*)&g[(size_t)c * DD + f4];
        float* yp = &y[(size_t)r * DD + f4];
        atomicAdd(yp + 0, v * gv.x);
        atomicAdd(yp + 1, v * gv.y);
        atomicAdd(yp + 2, v * gv.z);
        atomicAdd(yp + 3, v * gv.w);
    }
}

// ---------------- elementwise tanh in place ----------------
__global__ __launch_bounds__(256) void tanh_ip(float* __restrict__ y) {
    const size_t n4 = (size_t)NN * DD / 4;
    for (size_t i = (size_t)blockIdx.x * 256 + threadIdx.x; i < n4;
         i += (size_t)gridDim.x * 256) {
        float4 v = ((float4*)y)[i];
        v.x = tanhf(v.x);
        v.y = tanhf(v.y);
        v.z = tanhf(v.z);
        v.w = tanhf(v.w);
        ((float4*)y)[i] = v;
    }
}

// ---------------- out = tanh(out + x) ----------------
__global__ __launch_bounds__(256) void final_act(float* __restrict__ out,
                                                 const float* __restrict__ x) {
    const size_t n4 = (size_t)NN * DD / 4;
    for (size_t i = (size_t)blockIdx.x * 256 + threadIdx.x; i < n4;
         i += (size_t)gridDim.x * 256) {
        const float4 a = ((const float4*)x)[i];
        float4 v = ((float4*)out)[i];
        v.x = tanhf(v.x + a.x);
        v.y = tanhf(v.y + a.y);
        v.z = tanhf(v.z + a.z);
        v.w = tanhf(v.w + a.w);
        ((float4*)out)[i] = v;
    }
}

extern "C" void kernel_launch(void* const* d_in, const int* in_sizes, int n_in,
                              void* d_out, int out_size, void* d_ws, size_t ws_size,
                              hipStream_t stream) {
    const float* x    = (const float*)d_in[0];
    const float* Ws   = (const float*)d_in[1];
    const float* bs   = (const float*)d_in[2];
    const float* vals = (const float*)d_in[3];
    const int*   rows = (const int*)d_in[4];
    const int*   cols = (const int*)d_in[5];
    float* out = (float*)d_out;

    float* g = (float*)d_ws;                 // 51.2 MB GEMM output / spmm gather src
    float* y = g + (size_t)NN * DD;          // 51.2 MB layer-0 spmm accumulator
    const size_t fbytes = (size_t)NN * DD * sizeof(float);

    // d_out doubles as h_sum accumulator (layer-1 spmms atomic-add into it)
    hipMemsetAsync(out, 0, fbytes, stream);

    for (int s = 0; s < 2; ++s) {
        const float* W0 = Ws + (size_t)(s * 2 + 0) * DD * DD;
        const float* W1 = Ws + (size_t)(s * 2 + 1) * DD * DD;
        const float* b0 = bs + (size_t)(s * 2 + 0) * DD;
        const float* b1 = bs + (size_t)(s * 2 + 1) * DD;
        const float* vs = vals + (size_t)s * NE;
        const int*   rs = rows + (size_t)s * NE;
        const int*   cs = cols + (size_t)s * NE;

        // layer 0: g = x @ W0^T + b0 ; y = A g ; y = tanh(y)
        gemm_xwt<<<(NN + 63) / 64, 256, 0, stream>>>(x, W0, b0, g);
        hipMemsetAsync(y, 0, fbytes, stream);
        spmm_at<<<8192, 256, 0, stream>>>(vs, rs, cs, g, y);
        tanh_ip<<<4096, 256, 0, stream>>>(y);

        // layer 1: g = y @ W1^T + b1 ; out += A g
        gemm_xwt<<<(NN + 63) / 64, 256, 0, stream>>>(y, W1, b1, g);
        spmm_at<<<8192, 256, 0, stream>>>(vs, rs, cs, g, out);
    }

    // out = tanh(out + x)
    final_act<<<4096, 256, 0, stream>>>(out, x);
}

// Round 2
// 2009.392 us; speedup vs baseline: 10.8825x; 10.8825x over previous
//
#include <hip/hip_runtime.h>

#define NN 100000
#define DD 128
#define NE 3200000
#define SCAN_B 1024

// ---------------- GEMM: g[m,n] = sum_k h[m,k] * W[n,k] + b[n] ----------------
__global__ __launch_bounds__(256) void gemm_xwt(const float* __restrict__ h,
                                                const float* __restrict__ W,
                                                const float* __restrict__ b,
                                                float* __restrict__ g) {
    __shared__ float Wl[128 * 128];
    const int t = threadIdx.x;
    for (int i = t * 4; i < 128 * 128; i += 256 * 4) {
        const int n = i >> 7;
        const int k = i & 127;
        const float4 w = *(const float4*)&W[i];
        *(float4*)&Wl[(n << 7) + ((((k >> 2) ^ (n & 7)) << 2))] = w;
    }
    __syncthreads();

    const int tc = t & 15;
    const int tr = t >> 4;
    const int r0 = blockIdx.x * 64 + tr * 4;

    int rr[4];
#pragma unroll
    for (int j = 0; j < 4; ++j) rr[j] = min(r0 + j, NN - 1);

    float acc[4][8];
#pragma unroll
    for (int i = 0; i < 8; ++i) {
        const float bv = b[tc + 16 * i];
#pragma unroll
        for (int j = 0; j < 4; ++j) acc[j][i] = bv;
    }

#pragma unroll 2
    for (int k0 = 0; k0 < 128; k0 += 4) {
        float4 hv[4];
#pragma unroll
        for (int j = 0; j < 4; ++j)
            hv[j] = *(const float4*)&h[(size_t)rr[j] * DD + k0];
#pragma unroll
        for (int i = 0; i < 8; ++i) {
            const int n = tc + 16 * i;
            const float4 wv =
                *(const float4*)&Wl[(n << 7) + ((((k0 >> 2) ^ (n & 7)) << 2))];
#pragma unroll
            for (int j = 0; j < 4; ++j) {
                acc[j][i] += hv[j].x * wv.x;
                acc[j][i] += hv[j].y * wv.y;
                acc[j][i] += hv[j].z * wv.z;
                acc[j][i] += hv[j].w * wv.w;
            }
        }
    }

#pragma unroll
    for (int j = 0; j < 4; ++j) {
        const int r = r0 + j;
        if (r < NN) {
#pragma unroll
            for (int i = 0; i < 8; ++i)
                g[(size_t)r * DD + tc + 16 * i] = acc[j][i];
        }
    }
}

// ---------------- CSR build ----------------
__global__ __launch_bounds__(256) void edge_count(const int* __restrict__ rows,
                                                  int* __restrict__ cnt) {
    for (int e = blockIdx.x * 256 + threadIdx.x; e < NE; e += gridDim.x * 256)
        atomicAdd(&cnt[rows[e]], 1);
}

// block-level exclusive scan partials; sums[bid] = block total
__global__ __launch_bounds__(SCAN_B) void scan1(const int* __restrict__ cnt,
                                                int* __restrict__ rp,
                                                int* __restrict__ sums) {
    __shared__ int tmp[SCAN_B];
    const int tid = threadIdx.x;
    const int i = blockIdx.x * SCAN_B + tid;
    const int v = (i < NN) ? cnt[i] : 0;
    tmp[tid] = v;
    __syncthreads();
    for (int off = 1; off < SCAN_B; off <<= 1) {
        const int t = (tid >= off) ? tmp[tid - off] : 0;
        __syncthreads();
        tmp[tid] += t;
        __syncthreads();
    }
    if (i < NN) rp[i] = tmp[tid] - v;  // exclusive
    if (tid == SCAN_B - 1) sums[blockIdx.x] = tmp[tid];
}

__global__ __launch_bounds__(128) void scan2(int* __restrict__ sums, int nb) {
    __shared__ int tmp[128];
    const int tid = threadIdx.x;
    const int v = (tid < nb) ? sums[tid] : 0;
    tmp[tid] = v;
    __syncthreads();
    for (int off = 1; off < 128; off <<= 1) {
        const int t = (tid >= off) ? tmp[tid - off] : 0;
        __syncthreads();
        tmp[tid] += t;
        __syncthreads();
    }
    if (tid < nb) sums[tid] = tmp[tid] - v;  // exclusive block offsets
}

__global__ __launch_bounds__(SCAN_B) void scan3(int* __restrict__ rp,
                                                const int* __restrict__ sums) {
    const int i = blockIdx.x * SCAN_B + threadIdx.x;
    if (i < NN) rp[i] += sums[blockIdx.x];
    if (i == 0) rp[NN] = NE;
}

// scatter permuted (val,col) pairs (PACKED=1) or edge index (PACKED=0)
template <int PACKED>
__global__ __launch_bounds__(256) void edge_scatter(const float* __restrict__ vals,
                                                    const int* __restrict__ rows,
                                                    const int* __restrict__ cols,
                                                    int* __restrict__ cur,
                                                    float* __restrict__ ev,
                                                    int* __restrict__ ec,
                                                    int* __restrict__ perm) {
    for (int e = blockIdx.x * 256 + threadIdx.x; e < NE; e += gridDim.x * 256) {
        const int r = rows[e];
        const int pos = atomicAdd(&cur[r], 1);
        if (PACKED) {
            ev[pos] = vals[e];
            ec[pos] = cols[e];
        } else {
            perm[pos] = e;
        }
    }
}

// ---------------- row-parallel CSR SpMM ----------------
// MODE: 0 = y[r]=tanh(sum), 1 = y[r]=sum, 2 = y[r]+=sum
// IND:  0 = packed ev/ec, 1 = indirect via perm
template <int MODE, int IND>
__global__ __launch_bounds__(256) void spmm_csr(const int* __restrict__ rp,
                                                const float* __restrict__ ev,
                                                const int* __restrict__ ec,
                                                const int* __restrict__ perm,
                                                const float* __restrict__ vals,
                                                const int* __restrict__ cols,
                                                const float* __restrict__ g,
                                                float* __restrict__ y) {
    const int w = (blockIdx.x << 2) + (threadIdx.x >> 6);
    if (w >= NN) return;
    const int lane = threadIdx.x & 63;
    const int beg = rp[w];
    const int end = rp[w + 1];
    float2 acc = {0.f, 0.f};
    int j = beg;
    for (; j + 4 <= end; j += 4) {
        float v[4];
        int c[4];
#pragma unroll
        for (int q = 0; q < 4; ++q) {
            if (IND) {
                const int pe = perm[j + q];
                v[q] = vals[pe];
                c[q] = cols[pe];
            } else {
                v[q] = ev[j + q];
                c[q] = ec[j + q];
            }
        }
        float2 gv[4];
#pragma unroll
        for (int q = 0; q < 4; ++q)
            gv[q] = *(const float2*)&g[(size_t)c[q] * DD + (lane << 1)];
#pragma unroll
        for (int q = 0; q < 4; ++q) {
            acc.x += v[q] * gv[q].x;
            acc.y += v[q] * gv[q].y;
        }
    }
    for (; j < end; ++j) {
        float v;
        int c;
        if (IND) {
            const int pe = perm[j];
            v = vals[pe];
            c = cols[pe];
        } else {
            v = ev[j];
            c = ec[j];
        }
        const float2 gv = *(const float2*)&g[(size_t)c * DD + (lane << 1)];
        acc.x += v * gv.x;
        acc.y += v * gv.y;
    }
    float* yp = &y[(size_t)w * DD + (lane << 1)];
    if (MODE == 0) {
        float2 r;
        r.x = tanhf(acc.x);
        r.y = tanhf(acc.y);
        *(float2*)yp = r;
    } else if (MODE == 1) {
        *(float2*)yp = acc;
    } else {
        float2 o = *(const float2*)yp;
        o.x += acc.x;
        o.y += acc.y;
        *(float2*)yp = o;
    }
}

// ---------------- atomic fallback SpMM (tier 2) ----------------
__global__ __launch_bounds__(256) void spmm_at(const float* __restrict__ vals,
                                               const int* __restrict__ rows,
                                               const int* __restrict__ cols,
                                               const float* __restrict__ g,
                                               float* __restrict__ y) {
    const int gid = blockIdx.x * 256 + threadIdx.x;
    const int f4 = (gid & 31) << 2;
    const int estride = (gridDim.x * 256) >> 5;
    for (int e = gid >> 5; e < NE; e += estride) {
        const float v = vals[e];
        const int r = rows[e];
        const int c = cols[e];
        const float4 gv = *(const float4*)&g[(size_t)c * DD + f4];
        float* yp = &y[(size_t)r * DD + f4];
        atomicAdd(yp + 0, v * gv.x);
        atomicAdd(yp + 1, v * gv.y);
        atomicAdd(yp + 2, v * gv.z);
        atomicAdd(yp + 3, v * gv.w);
    }
}

__global__ __launch_bounds__(256) void tanh_ip(float* __restrict__ y) {
    const size_t n4 = (size_t)NN * DD / 4;
    for (size_t i = (size_t)blockIdx.x * 256 + threadIdx.x; i < n4;
         i += (size_t)gridDim.x * 256) {
        float4 v = ((float4*)y)[i];
        v.x = tanhf(v.x);
        v.y = tanhf(v.y);
        v.z = tanhf(v.z);
        v.w = tanhf(v.w);
        ((float4*)y)[i] = v;
    }
}

__global__ __launch_bounds__(256) void final_act(float* __restrict__ out,
                                                 const float* __restrict__ x) {
    const size_t n4 = (size_t)NN * DD / 4;
    for (size_t i = (size_t)blockIdx.x * 256 + threadIdx.x; i < n4;
         i += (size_t)gridDim.x * 256) {
        const float4 a = ((const float4*)x)[i];
        float4 v = ((float4*)out)[i];
        v.x = tanhf(v.x + a.x);
        v.y = tanhf(v.y + a.y);
        v.z = tanhf(v.z + a.z);
        v.w = tanhf(v.w + a.w);
        ((float4*)out)[i] = v;
    }
}

extern "C" void kernel_launch(void* const* d_in, const int* in_sizes, int n_in,
                              void* d_out, int out_size, void* d_ws, size_t ws_size,
                              hipStream_t stream) {
    const float* x    = (const float*)d_in[0];
    const float* Ws   = (const float*)d_in[1];
    const float* bs   = (const float*)d_in[2];
    const float* vals = (const float*)d_in[3];
    const int*   rows = (const int*)d_in[4];
    const int*   cols = (const int*)d_in[5];
    float* out = (float*)d_out;

    const size_t FB   = (size_t)NN * DD * sizeof(float);   // 51.2 MB
    const size_t RPB  = ((size_t)(NN + 1) * 4 + 127) & ~(size_t)127;
    const size_t EVB  = (size_t)NE * 4;
    const size_t ECB  = (size_t)NE * 4;
    const size_t CNTB = ((size_t)NN * 4 + 127) & ~(size_t)127;
    const size_t SUMB = 512;

    const size_t need_packed = 2 * FB + 2 * (RPB + EVB + ECB) + CNTB + SUMB;
    const size_t need_perm   = 2 * FB + 2 * (RPB + EVB) + CNTB + SUMB;

    char* p = (char*)d_ws;
    float* g = (float*)p; p += FB;
    float* y = (float*)p; p += FB;

    const int nb = (NN + SCAN_B - 1) / SCAN_B;

    if (ws_size >= need_packed || ws_size >= need_perm) {
        const int packed = (ws_size >= need_packed) ? 1 : 0;

        int*   rp_[2];
        float* ev_[2];
        int*   ec_[2];
        int*   pm_[2];
        for (int s = 0; s < 2; ++s) {
            rp_[s] = (int*)p; p += RPB;
            if (packed) {
                ev_[s] = (float*)p; p += EVB;
                ec_[s] = (int*)p;   p += ECB;
                pm_[s] = nullptr;
            } else {
                pm_[s] = (int*)p; p += EVB;
                ev_[s] = nullptr;
                ec_[s] = nullptr;
            }
        }
        int* cnt  = (int*)p; p += CNTB;
        int* sums = (int*)p; p += SUMB;

        // ---- build CSR per support ----
        for (int s = 0; s < 2; ++s) {
            const int* rs = rows + (size_t)s * NE;
            const int* cs = cols + (size_t)s * NE;
            const float* vs = vals + (size_t)s * NE;
            hipMemsetAsync(cnt, 0, (size_t)NN * 4, stream);
            edge_count<<<8192, 256, 0, stream>>>(rs, cnt);
            scan1<<<nb, SCAN_B, 0, stream>>>(cnt, rp_[s], sums);
            scan2<<<1, 128, 0, stream>>>(sums, nb);
            scan3<<<nb, SCAN_B, 0, stream>>>(rp_[s], sums);
            // cnt becomes the running cursor
            hipMemcpyAsync(cnt, rp_[s], (size_t)NN * 4,
                           hipMemcpyDeviceToDevice, stream);
            if (packed)
                edge_scatter<1><<<8192, 256, 0, stream>>>(vs, rs, cs, cnt,
                                                          ev_[s], ec_[s], nullptr);
            else
                edge_scatter<0><<<8192, 256, 0, stream>>>(vs, rs, cs, cnt,
                                                          nullptr, nullptr, pm_[s]);
        }

        const int sgrid = (NN + 3) / 4;
        for (int s = 0; s < 2; ++s) {
            const float* W0 = Ws + (size_t)(s * 2 + 0) * DD * DD;
            const float* W1 = Ws + (size_t)(s * 2 + 1) * DD * DD;
            const float* b0 = bs + (size_t)(s * 2 + 0) * DD;
            const float* b1 = bs + (size_t)(s * 2 + 1) * DD;
            const float* vs = vals + (size_t)s * NE;
            const int*   cs = cols + (size_t)s * NE;

            gemm_xwt<<<(NN + 63) / 64, 256, 0, stream>>>(x, W0, b0, g);
            if (packed)
                spmm_csr<0, 0><<<sgrid, 256, 0, stream>>>(rp_[s], ev_[s], ec_[s],
                                                          nullptr, vs, cs, g, y);
            else
                spmm_csr<0, 1><<<sgrid, 256, 0, stream>>>(rp_[s], nullptr, nullptr,
                                                          pm_[s], vs, cs, g, y);
            gemm_xwt<<<(NN + 63) / 64, 256, 0, stream>>>(y, W1, b1, g);
            if (s == 0) {
                if (packed)
                    spmm_csr<1, 0><<<sgrid, 256, 0, stream>>>(rp_[s], ev_[s], ec_[s],
                                                              nullptr, vs, cs, g, out);
                else
                    spmm_csr<1, 1><<<sgrid, 256, 0, stream>>>(rp_[s], nullptr, nullptr,
                                                              pm_[s], vs, cs, g, out);
            } else {
                if (packed)
                    spmm_csr<2, 0><<<sgrid, 256, 0, stream>>>(rp_[s], ev_[s], ec_[s],
                                                              nullptr, vs, cs, g, out);
                else
                    spmm_csr<2, 1><<<sgrid, 256, 0, stream>>>(rp_[s], nullptr, nullptr,
                                                              pm_[s], vs, cs, g, out);
            }
        }
        final_act<<<4096, 256, 0, stream>>>(out, x);
        return;
    }

    // ---- tier 2 fallback: atomic SpMM (known-correct, ws >= 2*FB) ----
    hipMemsetAsync(out, 0, FB, stream);
    for (int s = 0; s < 2; ++s) {
        const float* W0 = Ws + (size_t)(s * 2 + 0) * DD * DD;
        const float* W1 = Ws + (size_t)(s * 2 + 1) * DD * DD;
        const float* b0 = bs + (size_t)(s * 2 + 0) * DD;
        const float* b1 = bs + (size_t)(s * 2 + 1) * DD;
        const float* vs = vals + (size_t)s * NE;
        const int*   rs = rows + (size_t)s * NE;
        const int*   cs = cols + (size_t)s * NE;

        gemm_xwt<<<(NN + 63) / 64, 256, 0, stream>>>(x, W0, b0, g);
        hipMemsetAsync(y, 0, FB, stream);
        spmm_at<<<8192, 256, 0, stream>>>(vs, rs, cs, g, y);
        tanh_ip<<<4096, 256, 0, stream>>>(y);
        gemm_xwt<<<(NN + 63) / 64, 256, 0, stream>>>(y, W1, b1, g);
        spmm_at<<<8192, 256, 0, stream>>>(vs, rs, cs, g, out);
    }
    final_act<<<4096, 256, 0, stream>>>(out, x);
}

// Round 3
// 1861.209 us; speedup vs baseline: 11.7490x; 1.0796x over previous
//
#include <hip/hip_runtime.h>

#define NN 100000
#define DD 128
#define NE 3200000
#define SCAN_B 1024

// ---------------- GEMM: g[m,n] = sum_k h[m,k] * W[n,k] + b[n] ----------------
__global__ __launch_bounds__(256) void gemm_xwt(const float* __restrict__ h,
                                                const float* __restrict__ W,
                                                const float* __restrict__ b,
                                                float* __restrict__ g) {
    __shared__ float Wl[128 * 128];
    const int t = threadIdx.x;
    for (int i = t * 4; i < 128 * 128; i += 256 * 4) {
        const int n = i >> 7;
        const int k = i & 127;
        const float4 w = *(const float4*)&W[i];
        *(float4*)&Wl[(n << 7) + ((((k >> 2) ^ (n & 7)) << 2))] = w;
    }
    __syncthreads();

    const int tc = t & 15;
    const int tr = t >> 4;
    const int r0 = blockIdx.x * 64 + tr * 4;

    int rr[4];
#pragma unroll
    for (int j = 0; j < 4; ++j) rr[j] = min(r0 + j, NN - 1);

    float acc[4][8];
#pragma unroll
    for (int i = 0; i < 8; ++i) {
        const float bv = b[tc + 16 * i];
#pragma unroll
        for (int j = 0; j < 4; ++j) acc[j][i] = bv;
    }

#pragma unroll 2
    for (int k0 = 0; k0 < 128; k0 += 4) {
        float4 hv[4];
#pragma unroll
        for (int j = 0; j < 4; ++j)
            hv[j] = *(const float4*)&h[(size_t)rr[j] * DD + k0];
#pragma unroll
        for (int i = 0; i < 8; ++i) {
            const int n = tc + 16 * i;
            const float4 wv =
                *(const float4*)&Wl[(n << 7) + ((((k0 >> 2) ^ (n & 7)) << 2))];
#pragma unroll
            for (int j = 0; j < 4; ++j) {
                acc[j][i] += hv[j].x * wv.x;
                acc[j][i] += hv[j].y * wv.y;
                acc[j][i] += hv[j].z * wv.z;
                acc[j][i] += hv[j].w * wv.w;
            }
        }
    }

#pragma unroll
    for (int j = 0; j < 4; ++j) {
        const int r = r0 + j;
        if (r < NN) {
#pragma unroll
            for (int i = 0; i < 8; ++i)
                g[(size_t)r * DD + tc + 16 * i] = acc[j][i];
        }
    }
}

// ---------------- CSR build (both supports per dispatch) ----------------
__global__ __launch_bounds__(256) void edge_count2(const int* __restrict__ rows,
                                                   int* __restrict__ cnt2) {
    for (int e = blockIdx.x * 256 + threadIdx.x; e < 2 * NE;
         e += gridDim.x * 256) {
        const int soff = (e >= NE) ? NN : 0;
        atomicAdd(&cnt2[soff + rows[e]], 1);
    }
}

// grid = 2*nb blocks; support = bid / nb
__global__ __launch_bounds__(SCAN_B) void scan1(const int* __restrict__ cnt2,
                                                int* __restrict__ rp2,
                                                int* __restrict__ sums2,
                                                int nb) {
    __shared__ int tmp[SCAN_B];
    const int s = blockIdx.x / nb;
    const int blk = blockIdx.x % nb;
    const int tid = threadIdx.x;
    const int i = blk * SCAN_B + tid;
    const int v = (i < NN) ? cnt2[s * NN + i] : 0;
    tmp[tid] = v;
    __syncthreads();
    for (int off = 1; off < SCAN_B; off <<= 1) {
        const int t = (tid >= off) ? tmp[tid - off] : 0;
        __syncthreads();
        tmp[tid] += t;
        __syncthreads();
    }
    if (i < NN) rp2[s * (NN + 1) + i] = tmp[tid] - v;  // exclusive
    if (tid == SCAN_B - 1) sums2[s * 128 + blk] = tmp[tid];
}

// grid = 2 blocks; bid = support
__global__ __launch_bounds__(128) void scan2(int* __restrict__ sums2, int nb) {
    __shared__ int tmp[128];
    const int tid = threadIdx.x;
    int* sums = sums2 + blockIdx.x * 128;
    const int v = (tid < nb) ? sums[tid] : 0;
    tmp[tid] = v;
    __syncthreads();
    for (int off = 1; off < 128; off <<= 1) {
        const int t = (tid >= off) ? tmp[tid - off] : 0;
        __syncthreads();
        tmp[tid] += t;
        __syncthreads();
    }
    if (tid < nb) sums[tid] = tmp[tid] - v;  // exclusive block offsets
}

// grid = 2*nb; finalize rp and write cursor copy
__global__ __launch_bounds__(SCAN_B) void scan3(int* __restrict__ rp2,
                                                const int* __restrict__ sums2,
                                                int* __restrict__ cur2,
                                                int nb) {
    const int s = blockIdx.x / nb;
    const int blk = blockIdx.x % nb;
    const int i = blk * SCAN_B + threadIdx.x;
    if (i < NN) {
        const int v = rp2[s * (NN + 1) + i] + sums2[s * 128 + blk];
        rp2[s * (NN + 1) + i] = v;
        cur2[s * NN + i] = v;
    }
    if (i == 0) rp2[s * (NN + 1) + NN] = NE;
}

// scatter packed (col,val) pairs for both supports
__global__ __launch_bounds__(256) void edge_scatter2(const float* __restrict__ vals,
                                                     const int* __restrict__ rows,
                                                     const int* __restrict__ cols,
                                                     int* __restrict__ cur2,
                                                     int2* __restrict__ pairs) {
    for (int e = blockIdx.x * 256 + threadIdx.x; e < 2 * NE;
         e += gridDim.x * 256) {
        const int is1 = (e >= NE);
        const int pos = atomicAdd(&cur2[is1 * NN + rows[e]], 1);
        pairs[(size_t)is1 * NE + pos] = make_int2(cols[e], __float_as_int(vals[e]));
    }
}

// ---------------- row-parallel CSR SpMM ----------------
// MODE: 0 = y[r]=tanh(acc), 1 = y[r]=acc, 3 = y[r]=tanh(y[r]+acc+x[r])
template <int MODE>
__global__ __launch_bounds__(256) void spmm_csr(const int* __restrict__ rp,
                                                const int2* __restrict__ pairs,
                                                const float* __restrict__ g,
                                                const float* __restrict__ x,
                                                float* __restrict__ y) {
    const int w = (blockIdx.x << 2) + (threadIdx.x >> 6);
    if (w >= NN) return;
    const int lane = threadIdx.x & 63;
    const int beg = rp[w];
    const int end = rp[w + 1];
    float2 acc = {0.f, 0.f};
    int j = beg;
    for (; j + 4 <= end; j += 4) {
        int2 p[4];
#pragma unroll
        for (int q = 0; q < 4; ++q) p[q] = pairs[j + q];
        float2 gv[4];
#pragma unroll
        for (int q = 0; q < 4; ++q)
            gv[q] = *(const float2*)&g[(size_t)p[q].x * DD + (lane << 1)];
#pragma unroll
        for (int q = 0; q < 4; ++q) {
            const float v = __int_as_float(p[q].y);
            acc.x += v * gv[q].x;
            acc.y += v * gv[q].y;
        }
    }
    for (; j < end; ++j) {
        const int2 p = pairs[j];
        const float v = __int_as_float(p.y);
        const float2 gv = *(const float2*)&g[(size_t)p.x * DD + (lane << 1)];
        acc.x += v * gv.x;
        acc.y += v * gv.y;
    }
    float* yp = &y[(size_t)w * DD + (lane << 1)];
    if (MODE == 0) {
        float2 r;
        r.x = tanhf(acc.x);
        r.y = tanhf(acc.y);
        *(float2*)yp = r;
    } else if (MODE == 1) {
        *(float2*)yp = acc;
    } else {
        const float2 xv = *(const float2*)&x[(size_t)w * DD + (lane << 1)];
        const float2 o = *(const float2*)yp;
        float2 r;
        r.x = tanhf(o.x + acc.x + xv.x);
        r.y = tanhf(o.y + acc.y + xv.y);
        *(float2*)yp = r;
    }
}

// ---------------- atomic fallback SpMM (tier 2) ----------------
__global__ __launch_bounds__(256) void spmm_at(const float* __restrict__ vals,
                                               const int* __restrict__ rows,
                                               const int* __restrict__ cols,
                                               const float* __restrict__ g,
                                               float* __restrict__ y) {
    const int gid = blockIdx.x * 256 + threadIdx.x;
    const int f4 = (gid & 31) << 2;
    const int estride = (gridDim.x * 256) >> 5;
    for (int e = gid >> 5; e < NE; e += estride) {
        const float v = vals[e];
        const int r = rows[e];
        const int c = cols[e];
        const float4 gv = *(const float4*)&g[(size_t)c * DD + f4];
        float* yp = &y[(size_t)r * DD + f4];
        atomicAdd(yp + 0, v * gv.x);
        atomicAdd(yp + 1, v * gv.y);
        atomicAdd(yp + 2, v * gv.z);
        atomicAdd(yp + 3, v * gv.w);
    }
}

__global__ __launch_bounds__(256) void tanh_ip(float* __restrict__ y) {
    const size_t n4 = (size_t)NN * DD / 4;
    for (size_t i = (size_t)blockIdx.x * 256 + threadIdx.x; i < n4;
         i += (size_t)gridDim.x * 256) {
        float4 v = ((float4*)y)[i];
        v.x = tanhf(v.x);
        v.y = tanhf(v.y);
        v.z = tanhf(v.z);
        v.w = tanhf(v.w);
        ((float4*)y)[i] = v;
    }
}

__global__ __launch_bounds__(256) void final_act(float* __restrict__ out,
                                                 const float* __restrict__ x) {
    const size_t n4 = (size_t)NN * DD / 4;
    for (size_t i = (size_t)blockIdx.x * 256 + threadIdx.x; i < n4;
         i += (size_t)gridDim.x * 256) {
        const float4 a = ((const float4*)x)[i];
        float4 v = ((float4*)out)[i];
        v.x = tanhf(v.x + a.x);
        v.y = tanhf(v.y + a.y);
        v.z = tanhf(v.z + a.z);
        v.w = tanhf(v.w + a.w);
        ((float4*)out)[i] = v;
    }
}

extern "C" void kernel_launch(void* const* d_in, const int* in_sizes, int n_in,
                              void* d_out, int out_size, void* d_ws, size_t ws_size,
                              hipStream_t stream) {
    const float* x    = (const float*)d_in[0];
    const float* Ws   = (const float*)d_in[1];
    const float* bs   = (const float*)d_in[2];
    const float* vals = (const float*)d_in[3];
    const int*   rows = (const int*)d_in[4];
    const int*   cols = (const int*)d_in[5];
    float* out = (float*)d_out;

    const size_t FB    = (size_t)NN * DD * sizeof(float);          // 51.2 MB
    const size_t RP2B  = ((size_t)2 * (NN + 1) * 4 + 127) & ~(size_t)127;
    const size_t PAIRB = (size_t)2 * NE * 8;                       // 51.2 MB
    const size_t CNTB  = ((size_t)2 * NN * 4 + 127) & ~(size_t)127;
    const size_t SUMB  = 1024;

    const size_t need_csr = 2 * FB + RP2B + PAIRB + 2 * CNTB + SUMB;  // ~156 MB

    char* p = (char*)d_ws;
    float* g = (float*)p; p += FB;
    float* y = (float*)p; p += FB;

    const int nb = (NN + SCAN_B - 1) / SCAN_B;  // 98

    if (ws_size >= need_csr) {
        int*  rp2   = (int*)p;  p += RP2B;
        int2* pairs = (int2*)p; p += PAIRB;
        int*  cnt2  = (int*)p;  p += CNTB;
        int*  cur2  = (int*)p;  p += CNTB;
        int*  sums2 = (int*)p;  p += SUMB;

        // ---- build CSR for both supports ----
        hipMemsetAsync(cnt2, 0, (size_t)2 * NN * 4, stream);
        edge_count2<<<8192, 256, 0, stream>>>(rows, cnt2);
        scan1<<<2 * nb, SCAN_B, 0, stream>>>(cnt2, rp2, sums2, nb);
        scan2<<<2, 128, 0, stream>>>(sums2, nb);
        scan3<<<2 * nb, SCAN_B, 0, stream>>>(rp2, sums2, cur2, nb);
        edge_scatter2<<<8192, 256, 0, stream>>>(vals, rows, cols, cur2, pairs);

        const int sgrid = (NN + 3) / 4;
        for (int s = 0; s < 2; ++s) {
            const float* W0 = Ws + (size_t)(s * 2 + 0) * DD * DD;
            const float* W1 = Ws + (size_t)(s * 2 + 1) * DD * DD;
            const float* b0 = bs + (size_t)(s * 2 + 0) * DD;
            const float* b1 = bs + (size_t)(s * 2 + 1) * DD;
            const int*  rp = rp2 + (size_t)s * (NN + 1);
            const int2* pr = pairs + (size_t)s * NE;

            // layer 0: g = x@W0^T+b0 ; y = tanh(A g)
            gemm_xwt<<<(NN + 63) / 64, 256, 0, stream>>>(x, W0, b0, g);
            spmm_csr<0><<<sgrid, 256, 0, stream>>>(rp, pr, g, nullptr, y);
            // layer 1: g = y@W1^T+b1 ; out (+)= A g
            gemm_xwt<<<(NN + 63) / 64, 256, 0, stream>>>(y, W1, b1, g);
            if (s == 0)
                spmm_csr<1><<<sgrid, 256, 0, stream>>>(rp, pr, g, nullptr, out);
            else  // fused: out = tanh(out + A g + x)
                spmm_csr<3><<<sgrid, 256, 0, stream>>>(rp, pr, g, x, out);
        }
        return;
    }

    // ---- fallback: atomic SpMM (ws >= 2*FB) ----
    hipMemsetAsync(out, 0, FB, stream);
    for (int s = 0; s < 2; ++s) {
        const float* W0 = Ws + (size_t)(s * 2 + 0) * DD * DD;
        const float* W1 = Ws + (size_t)(s * 2 + 1) * DD * DD;
        const float* b0 = bs + (size_t)(s * 2 + 0) * DD;
        const float* b1 = bs + (size_t)(s * 2 + 1) * DD;
        const float* vs = vals + (size_t)s * NE;
        const int*   rs = rows + (size_t)s * NE;
        const int*   cs = cols + (size_t)s * NE;

        gemm_xwt<<<(NN + 63) / 64, 256, 0, stream>>>(x, W0, b0, g);
        hipMemsetAsync(y, 0, FB, stream);
        spmm_at<<<8192, 256, 0, stream>>>(vs, rs, cs, g, y);
        tanh_ip<<<4096, 256, 0, stream>>>(y);
        gemm_xwt<<<(NN + 63) / 64, 256, 0, stream>>>(y, W1, b1, g);
        spmm_at<<<8192, 256, 0, stream>>>(vs, rs, cs, g, out);
    }
    final_act<<<4096, 256, 0, stream>>>(out, x);
}